// Round 13
// baseline (545.872 us; speedup 1.0000x reference)
//
#include <hip/hip_runtime.h>
#include <math.h>

#define BLK 256
#define CHUNK 8192
#define BSH 8
#define BNODES 256
#define MAXNB 256

typedef __attribute__((ext_vector_type(8))) short bf8_t;   // 8 bf16
typedef __attribute__((ext_vector_type(4))) float f4_t;    // MFMA acc

// ---------------------------------------------------------------------------
__device__ __forceinline__ unsigned short f2bf(float f) {
    unsigned u = __float_as_uint(f);
    u += 0x7FFFu + ((u >> 16) & 1u);
    return (unsigned short)(u >> 16);
}
__device__ __forceinline__ float bf2f(unsigned short b) {
    return __uint_as_float(((unsigned)b) << 16);
}

// ---------------------------------------------------------------------------
// Fallback-path probe; zeroes acc/done.
__global__ void detect_kernel(const int* __restrict__ idx, int E,
                              int* __restrict__ flag, float* __restrict__ acc,
                              int* __restrict__ done) {
    int t = threadIdx.x;  // 64 threads
    long long j = (long long)t * (E / 64);
    int hi = idx[2 * j + 1];
    unsigned long long b = __ballot(hi != 0);
    if (t == 0) { *flag = (b == 0ULL) ? 1 : 0; *acc = 0.f; *done = 0; }
}

// ---------------------------------------------------------------------------
// K1: per-block bucket histogram; claims per-bucket base via global atomicAdd
// into bucketFill (pre-zeroed by memset). i64 detection inlined.
__global__ __launch_bounds__(256) void bucket_hist_kernel(const int* __restrict__ idx,
                                                          int* __restrict__ bucketFill,
                                                          int* __restrict__ blockBase,
                                                          int E, int NB) {
    __shared__ int hist[MAXNB];
    __shared__ int i64s;
    int t = threadIdx.x;
    for (int i = t; i < NB; i += 256) hist[i] = 0;
    if (t < 64) {
        long long j = (long long)t * (E / 64);
        int hi = idx[2 * j + 1];
        unsigned long long b = __ballot(hi != 0);
        if (t == 0) i64s = (b == 0ULL) ? 1 : 0;
    }
    __syncthreads();
    bool i64 = i64s != 0;
    int e0 = blockIdx.x * CHUNK;
    int e1 = min(e0 + CHUNK, E);
    for (int e = e0 + t; e < e1; e += 256) {
        int d = i64 ? idx[2 * (E + e)] : idx[E + e];
        atomicAdd(&hist[d >> BSH], 1);
    }
    __syncthreads();
    for (int i = t; i < NB; i += 256)
        blockBase[blockIdx.x * NB + i] = atomicAdd(&bucketFill[i], hist[i]);
}

// K3: scatter edges into bucket-partitioned temp as contiguous runs.
// bucketBase derived in-block from bucketFill (NB<=256 scan).
__global__ __launch_bounds__(256) void bucket_scatter_kernel(const int* __restrict__ idx,
                                                             const float* __restrict__ ew,
                                                             const int* __restrict__ bucketFill,
                                                             const int* __restrict__ blockBase,
                                                             int2* __restrict__ temp,
                                                             int E, int NB) {
    __shared__ int base[MAXNB];
    __shared__ int fill[MAXNB];
    __shared__ int s[256];
    __shared__ int i64s;
    int t = threadIdx.x;
    int v = (t < NB) ? bucketFill[t] : 0;
    s[t] = v;
    if (t < 64) {
        long long j = (long long)t * (E / 64);
        int hi = idx[2 * j + 1];
        unsigned long long b = __ballot(hi != 0);
        if (t == 0) i64s = (b == 0ULL) ? 1 : 0;
    }
    __syncthreads();
    for (int off = 1; off < 256; off <<= 1) {
        int x = (t >= off) ? s[t - off] : 0;
        __syncthreads();
        s[t] += x;
        __syncthreads();
    }
    if (t < NB) {
        base[t] = (s[t] - v) + blockBase[blockIdx.x * NB + t];
        fill[t] = 0;
    }
    __syncthreads();
    bool i64 = i64s != 0;
    int e0 = blockIdx.x * CHUNK;
    int e1 = min(e0 + CHUNK, E);
    for (int e = e0 + t; e < e1; e += 256) {
        int s_, d;
        if (i64) { s_ = idx[2 * e]; d = idx[2 * (E + e)]; }
        else     { s_ = idx[e];     d = idx[E + e]; }
        float w = ew[e];
        int b = d >> BSH;
        int pos = base[b] + atomicAdd(&fill[b], 1);
        temp[pos] = make_int2(s_ | ((d & (BNODES - 1)) << 16), __float_as_int(w));
    }
}

// K4: per-bucket counting sort into packed CSR + dinv + row (one block/bucket)
// csrw[p] = src(16b) | raw bf16(w)<<16  (dinv folded into dense layers).
__global__ __launch_bounds__(512) void csr_build_kernel(const int2* __restrict__ temp,
                                                        const int* __restrict__ bucketFill,
                                                        unsigned* __restrict__ csrw,
                                                        int* __restrict__ row,
                                                        float* __restrict__ dinv,
                                                        int N, int NB, int E) {
    __shared__ int cnt[BNODES];
    __shared__ float dw[BNODES];
    __shared__ int offs[BNODES];
    __shared__ int sb[256];
    int bkt = blockIdx.x;
    int t = threadIdx.x;
    int node0 = bkt << BSH;
    int nn = min(BNODES, N - node0);
    if (t < BNODES) { cnt[t] = 0; dw[t] = 0.f; }
    if (t < 256) sb[t] = (t < NB) ? bucketFill[t] : 0;
    __syncthreads();
    for (int off = 1; off < 256; off <<= 1) {
        int x = 0;
        if (t < 256 && t >= off) x = sb[t - off];
        __syncthreads();
        if (t < 256) sb[t] += x;
        __syncthreads();
    }
    int p0 = (bkt > 0) ? sb[bkt - 1] : 0;
    int p1 = sb[bkt];
    for (int p = p0 + t; p < p1; p += 512) {
        int2 v = temp[p];
        int dl = (v.x >> 16) & (BNODES - 1);
        atomicAdd(&cnt[dl], 1);
        atomicAdd(&dw[dl], __int_as_float(v.y));
    }
    __syncthreads();
    int v = 0;
    if (t < BNODES) { v = cnt[t]; offs[t] = v; }
    __syncthreads();
    for (int off = 1; off < BNODES; off <<= 1) {
        int x = 0;
        if (t < BNODES && t >= off) x = offs[t - off];
        __syncthreads();
        if (t < BNODES) offs[t] += x;
        __syncthreads();
    }
    if (t < BNODES) {
        int excl = offs[t] - v;
        if (t < nn) {
            row[node0 + t] = p0 + excl;
            dinv[node0 + t] = rsqrtf(1.f + dw[t]);
        }
        offs[t] = excl;
    }
    if (bkt == NB - 1 && t == 0) row[N] = E;
    __syncthreads();
    if (t < BNODES) cnt[t] = 0;  // reuse as fill
    __syncthreads();
    for (int p = p0 + t; p < p1; p += 512) {
        int2 v2 = temp[p];
        int dl = (v2.x >> 16) & (BNODES - 1);
        int pos = p0 + offs[dl] + atomicAdd(&cnt[dl], 1);
        unsigned wb = (unsigned)v2.y;
        wb += 0x7FFFu + ((wb >> 16) & 1u);
        csrw[pos] = ((unsigned)v2.x & 0xFFFFu) | (wb & 0xFFFF0000u);
    }
}

// ---------------------------------------------------------------------------
// gather64: out[n,o] = bias[o] + dinv[n]*( h'[n,o] + sum w_raw*h'[src,o] )
__global__ __launch_bounds__(256) void gather64_kernel(const int* __restrict__ row,
                                                       const unsigned* __restrict__ csrw,
                                                       const unsigned short* __restrict__ h,
                                                       const float* __restrict__ dinv,
                                                       const float* __restrict__ bias,
                                                       float* __restrict__ out, int N) {
    int wid = (blockIdx.x * 256 + threadIdx.x) >> 6;
    int o = threadIdx.x & 63;
    if (wid >= N) return;
    float di = dinv[wid];
    int p0 = row[wid], p1 = row[wid + 1];
    const unsigned short* hb = h + o;
    float es[4] = {0.f, 0.f, 0.f, 0.f};
    for (int p = p0; p < p1; p += 64) {
        int q = p + o;
        unsigned pe = (q < p1) ? csrw[q] : 0u;
        int m = min(64, p1 - p);
        int mp = (m + 15) & ~15;
        for (int j = 0; j < mp; j += 16) {
            unsigned ee[16];
            float hh[16];
#pragma unroll
            for (int u = 0; u < 16; ++u) ee[u] = (unsigned)__shfl((int)pe, j + u, 64);
#pragma unroll
            for (int u = 0; u < 16; ++u) hh[u] = bf2f(hb[(ee[u] & 0xFFFFu) * 64]);
#pragma unroll
            for (int u = 0; u < 16; ++u)
                es[u & 3] = fmaf(__uint_as_float(ee[u] & 0xFFFF0000u), hh[u], es[u & 3]);
        }
    }
    float e01 = es[0] + es[1], e23 = es[2] + es[3];
    out[wid * 64 + o] = bias[o] + di * (bf2f(h[(size_t)wid * 64 + o]) + e01 + e23);
}

// gather32 + discriminator fused: compute z row (32 wide), tanh, tile to 128,
// add F, dot with Wd -> dpre' = dinv*(x@Wd) written as 2 bf16 per node.
__global__ __launch_bounds__(256) void gather32_disc_kernel(const int* __restrict__ row,
                                                            const unsigned* __restrict__ csrw,
                                                            const unsigned short* __restrict__ h,
                                                            const float* __restrict__ dinv,
                                                            const float* __restrict__ bias,
                                                            const float* __restrict__ F,
                                                            const float* __restrict__ Wd,
                                                            unsigned short* __restrict__ hout,
                                                            int N) {
    __shared__ float Ws[256];
    if (threadIdx.x < 256) Ws[threadIdx.x] = Wd[threadIdx.x];
    __syncthreads();
    int wid = (blockIdx.x * 256 + threadIdx.x) >> 6;
    int lane = threadIdx.x & 63;
    int o = lane & 31;
    int g = lane >> 5;
    if (wid >= N) return;
    float di = dinv[wid];
    int p0 = row[wid], p1 = row[wid + 1];
    const unsigned short* hb = h + o;
    float es[4] = {0.f, 0.f, 0.f, 0.f};
    for (int p = p0; p < p1; p += 64) {
        int q = p + lane;
        unsigned pe = (q < p1) ? csrw[q] : 0u;
        int m = min(64, p1 - p);
        int mp = (m + 15) & ~15;
        for (int j = g; j < mp; j += 16) {
            unsigned ee[8];
            float hh[8];
#pragma unroll
            for (int u = 0; u < 8; ++u) ee[u] = (unsigned)__shfl((int)pe, j + 2 * u, 64);
#pragma unroll
            for (int u = 0; u < 8; ++u) hh[u] = bf2f(hb[(ee[u] & 0xFFFFu) * 32]);
#pragma unroll
            for (int u = 0; u < 8; ++u)
                es[u & 3] = fmaf(__uint_as_float(ee[u] & 0xFFFF0000u), hh[u], es[u & 3]);
        }
    }
    float es_t = (es[0] + es[1]) + (es[2] + es[3]);
    es_t += __shfl_down(es_t, 32, 64);
    // lanes 0..31 hold full z row for this node
    float a0 = 0.f, a1 = 0.f;
    if (g == 0) {
        float zt = tanhf(bias[o] + di * (bf2f(h[wid * 32 + o]) + es_t));
        const float* fr = F + (size_t)wid * 128;
#pragma unroll
        for (int j = 0; j < 4; ++j) {
            int c = o + 32 * j;
            float xv = zt + fr[c];
            a0 = fmaf(xv, Ws[c * 2 + 0], a0);
            a1 = fmaf(xv, Ws[c * 2 + 1], a1);
        }
    }
#pragma unroll
    for (int off = 16; off > 0; off >>= 1) {
        a0 += __shfl_down(a0, off, 64);
        a1 += __shfl_down(a1, off, 64);
    }
    if (lane == 0) {
        ushort2 ov;
        ov.x = f2bf(di * a0);
        ov.y = f2bf(di * a1);
        ((ushort2*)hout)[wid] = ov;
    }
}

// gather2 + final reduction fused: d = relu(bd + di*(dpre'[n] + sum w*dpre'[src]));
// logit contribution d0*wfc[2n] + d1*wfc[2n+1] accumulated; last block -> sigmoid.
__global__ __launch_bounds__(256) void gather2_reduce_kernel(const int* __restrict__ row,
                                                             const unsigned* __restrict__ csrw,
                                                             const unsigned short* __restrict__ h,
                                                             const float* __restrict__ dinv,
                                                             const float* __restrict__ bias,
                                                             const float* __restrict__ wfc,
                                                             float* __restrict__ acc,
                                                             int* __restrict__ done,
                                                             const float* __restrict__ bfc,
                                                             float* __restrict__ out,
                                                             int N, int nblk) {
    const unsigned* hp = (const unsigned*)h;
    __shared__ float wsum[4];
    int wid = (blockIdx.x * 256 + threadIdx.x) >> 6;
    int lane = threadIdx.x & 63;
    float contrib = 0.f;
    if (wid < N) {
        float di = dinv[wid];
        int p0 = row[wid], p1 = row[wid + 1];
        float a0 = 0.f, a1 = 0.f, b0 = 0.f, b1 = 0.f;
        int p = p0 + lane;
        for (; p + 64 < p1; p += 128) {
            unsigned pe0 = csrw[p];
            unsigned pe1 = csrw[p + 64];
            unsigned hw0 = hp[pe0 & 0xFFFFu];
            unsigned hw1 = hp[pe1 & 0xFFFFu];
            float w0 = __uint_as_float(pe0 & 0xFFFF0000u);
            float w1 = __uint_as_float(pe1 & 0xFFFF0000u);
            a0 = fmaf(w0, __uint_as_float(hw0 << 16), a0);
            a1 = fmaf(w0, __uint_as_float(hw0 & 0xFFFF0000u), a1);
            b0 = fmaf(w1, __uint_as_float(hw1 << 16), b0);
            b1 = fmaf(w1, __uint_as_float(hw1 & 0xFFFF0000u), b1);
        }
        if (p < p1) {
            unsigned pe0 = csrw[p];
            unsigned hw0 = hp[pe0 & 0xFFFFu];
            float w0 = __uint_as_float(pe0 & 0xFFFF0000u);
            a0 = fmaf(w0, __uint_as_float(hw0 << 16), a0);
            a1 = fmaf(w0, __uint_as_float(hw0 & 0xFFFF0000u), a1);
        }
        a0 += b0; a1 += b1;
#pragma unroll
        for (int off = 32; off > 0; off >>= 1) {
            a0 += __shfl_down(a0, off, 64);
            a1 += __shfl_down(a1, off, 64);
        }
        if (lane == 0) {
            unsigned hw = hp[wid];
            float v0 = bias[0] + di * (__uint_as_float(hw << 16) + a0);
            float v1 = bias[1] + di * (__uint_as_float(hw & 0xFFFF0000u) + a1);
            contrib = fmaxf(v0, 0.f) * wfc[wid * 2 + 0] + fmaxf(v1, 0.f) * wfc[wid * 2 + 1];
        }
    }
    if ((threadIdx.x & 63) == 0) wsum[threadIdx.x >> 6] = contrib;
    __syncthreads();
    if (threadIdx.x == 0) {
        float s = (wsum[0] + wsum[1]) + (wsum[2] + wsum[3]);
        atomicAdd(acc, s);
        __threadfence();
        int old = atomicAdd(done, 1);
        if (old == nblk - 1) {
            float x = atomicAdd(acc, 0.f) + *bfc;
            out[0] = 1.f / (1.f + expf(-x));
        }
    }
}

// ---------------------------------------------------------------------------
// mm1 (MFMA): Y[N,64] = dinv[n] * (X[N,128] @ W[128,64]), bf16 out.
__global__ __launch_bounds__(256) void mm1_mfma_kernel(const float* __restrict__ X,
                                                       const float* __restrict__ W,
                                                       const float* __restrict__ dinv,
                                                       unsigned short* __restrict__ Y, int N) {
    __shared__ unsigned short Wf[4 * 4 * 64 * 8];  // [kt][ct][lane][j], 16 KB
    int t = threadIdx.x;
    for (int i = t; i < 8192; i += 256) {
        int j = i & 7;
        int lane = (i >> 3) & 63;
        int ct = (i >> 9) & 3;
        int kt = i >> 11;
        int k = kt * 32 + (lane >> 4) * 8 + j;
        int c = ct * 16 + (lane & 15);
        Wf[i] = f2bf(W[k * 64 + c]);
    }
    __syncthreads();
    int wave = t >> 6, lane = t & 63;
    int row0 = blockIdx.x * 64 + wave * 16;
    if (row0 >= N) return;
    int r = row0 + (lane & 15);
    int kq = (lane >> 4) * 8;
    bool rv = r < N;
    f4_t acc0 = {0.f, 0.f, 0.f, 0.f}, acc1 = acc0, acc2 = acc0, acc3 = acc0;
    const bf8_t* wf = (const bf8_t*)Wf;
#pragma unroll
    for (int kt = 0; kt < 4; ++kt) {
        bf8_t a = {0, 0, 0, 0, 0, 0, 0, 0};
        if (rv) {
            const float4* ap = (const float4*)(X + (size_t)r * 128 + kt * 32 + kq);
            float4 lo = ap[0], hi = ap[1];
            a[0] = (short)f2bf(lo.x); a[1] = (short)f2bf(lo.y);
            a[2] = (short)f2bf(lo.z); a[3] = (short)f2bf(lo.w);
            a[4] = (short)f2bf(hi.x); a[5] = (short)f2bf(hi.y);
            a[6] = (short)f2bf(hi.z); a[7] = (short)f2bf(hi.w);
        }
        bf8_t b0 = wf[(kt * 4 + 0) * 64 + lane];
        bf8_t b1 = wf[(kt * 4 + 1) * 64 + lane];
        bf8_t b2 = wf[(kt * 4 + 2) * 64 + lane];
        bf8_t b3 = wf[(kt * 4 + 3) * 64 + lane];
        acc0 = __builtin_amdgcn_mfma_f32_16x16x32_bf16(a, b0, acc0, 0, 0, 0);
        acc1 = __builtin_amdgcn_mfma_f32_16x16x32_bf16(a, b1, acc1, 0, 0, 0);
        acc2 = __builtin_amdgcn_mfma_f32_16x16x32_bf16(a, b2, acc2, 0, 0, 0);
        acc3 = __builtin_amdgcn_mfma_f32_16x16x32_bf16(a, b3, acc3, 0, 0, 0);
    }
    int colb = lane & 15;
    int rbase = row0 + (lane >> 4) * 4;
#pragma unroll
    for (int reg = 0; reg < 4; ++reg) {
        int rr = rbase + reg;
        if (rr < N) {
            float dv = dinv[rr];
            Y[(size_t)rr * 64 + colb]      = f2bf(dv * acc0[reg]);
            Y[(size_t)rr * 64 + 16 + colb] = f2bf(dv * acc1[reg]);
            Y[(size_t)rr * 64 + 32 + colb] = f2bf(dv * acc2[reg]);
            Y[(size_t)rr * 64 + 48 + colb] = f2bf(dv * acc3[reg]);
        }
    }
}

// mm2 (MFMA): Y[N,32] = dinv[n] * (relu(A[N,64]) @ W[64,32]), bf16 out.
__global__ __launch_bounds__(256) void mm2_mfma_kernel(const float* __restrict__ A,
                                                       const float* __restrict__ W,
                                                       const float* __restrict__ dinv,
                                                       unsigned short* __restrict__ Y, int N) {
    __shared__ unsigned short Wf[2 * 2 * 64 * 8];  // 4 KB
    int t = threadIdx.x;
    for (int i = t; i < 2048; i += 256) {
        int j = i & 7;
        int lane = (i >> 3) & 63;
        int ct = (i >> 9) & 1;
        int kt = i >> 10;
        int k = kt * 32 + (lane >> 4) * 8 + j;
        int c = ct * 16 + (lane & 15);
        Wf[i] = f2bf(W[k * 32 + c]);
    }
    __syncthreads();
    int wave = t >> 6, lane = t & 63;
    int row0 = blockIdx.x * 64 + wave * 16;
    if (row0 >= N) return;
    int r = row0 + (lane & 15);
    int kq = (lane >> 4) * 8;
    bool rv = r < N;
    f4_t acc0 = {0.f, 0.f, 0.f, 0.f}, acc1 = acc0;
    const bf8_t* wf = (const bf8_t*)Wf;
#pragma unroll
    for (int kt = 0; kt < 2; ++kt) {
        bf8_t a = {0, 0, 0, 0, 0, 0, 0, 0};
        if (rv) {
            const float4* ap = (const float4*)(A + (size_t)r * 64 + kt * 32 + kq);
            float4 lo = ap[0], hi = ap[1];
            a[0] = (short)f2bf(fmaxf(lo.x, 0.f)); a[1] = (short)f2bf(fmaxf(lo.y, 0.f));
            a[2] = (short)f2bf(fmaxf(lo.z, 0.f)); a[3] = (short)f2bf(fmaxf(lo.w, 0.f));
            a[4] = (short)f2bf(fmaxf(hi.x, 0.f)); a[5] = (short)f2bf(fmaxf(hi.y, 0.f));
            a[6] = (short)f2bf(fmaxf(hi.z, 0.f)); a[7] = (short)f2bf(fmaxf(hi.w, 0.f));
        }
        bf8_t b0 = wf[(kt * 2 + 0) * 64 + lane];
        bf8_t b1 = wf[(kt * 2 + 1) * 64 + lane];
        acc0 = __builtin_amdgcn_mfma_f32_16x16x32_bf16(a, b0, acc0, 0, 0, 0);
        acc1 = __builtin_amdgcn_mfma_f32_16x16x32_bf16(a, b1, acc1, 0, 0, 0);
    }
    int colb = lane & 15;
    int rbase = row0 + (lane >> 4) * 4;
#pragma unroll
    for (int reg = 0; reg < 4; ++reg) {
        int rr = rbase + reg;
        if (rr < N) {
            float dv = dinv[rr];
            Y[(size_t)rr * 32 + colb]      = f2bf(dv * acc0[reg]);
            Y[(size_t)rr * 32 + 16 + colb] = f2bf(dv * acc1[reg]);
        }
    }
}

// standalone disc (fallback path only)
__global__ __launch_bounds__(256) void disc_mm_kernel(const float* __restrict__ Z,
                                                      const float* __restrict__ F,
                                                      const float* __restrict__ Wd,
                                                      const float* __restrict__ dinv,
                                                      unsigned short* __restrict__ Y, int N) {
    __shared__ float Ws[256];
    if (threadIdx.x < 256) Ws[threadIdx.x] = Wd[threadIdx.x];
    __syncthreads();
    int n = blockIdx.x * 256 + threadIdx.x;
    if (n >= N) return;
    float zt[32];
#pragma unroll
    for (int j = 0; j < 32; ++j) zt[j] = tanhf(Z[n * 32 + j]);
    float a0 = 0.f, a1 = 0.f;
    const float* fr = F + (size_t)n * 128;
#pragma unroll 4
    for (int c = 0; c < 128; ++c) {
        float xv = zt[c & 31] + fr[c];
        a0 = fmaf(xv, Ws[c * 2 + 0], a0);
        a1 = fmaf(xv, Ws[c * 2 + 1], a1);
    }
    float dv = dinv[n];
    ushort2 o;
    o.x = f2bf(dv * a0); o.y = f2bf(dv * a1);
    ((ushort2*)Y)[n] = o;
}

// ---------------------------------------------------------------------------
// Fallback (atomic scatter) kernels — h' = dinv*h convention
__global__ void init_deg_kernel(float* __restrict__ deg, int N) {
    int n = blockIdx.x * BLK + threadIdx.x;
    if (n < N) deg[n] = 1.0f;
}

__global__ void edge_deg_kernel(const int* __restrict__ idx, const float* __restrict__ ew,
                                const int* __restrict__ flag, float* __restrict__ deg, int E) {
    int e = blockIdx.x * BLK + threadIdx.x;
    if (e >= E) return;
    int d = (*flag) ? idx[2 * (E + e)] : idx[E + e];
    atomicAdd(&deg[d], ew[e]);
}

__global__ void dinv_kernel(float* __restrict__ deg, int N) {
    int n = blockIdx.x * BLK + threadIdx.x;
    if (n < N) deg[n] = rsqrtf(deg[n]);
}

template <int WD>
__global__ void init_agg_kernel(const unsigned short* __restrict__ h, const float* __restrict__ dinv,
                                const float* __restrict__ bias, float* __restrict__ agg, int N) {
    int i = blockIdx.x * BLK + threadIdx.x;
    if (i >= N * WD) return;
    int n = i / WD, o = i % WD;
    float di = dinv[n];
    agg[i] = bias[o] + di * bf2f(h[i]);
}

template <int WD>
__global__ void edge_agg_kernel(const int* __restrict__ idx, const float* __restrict__ ew,
                                const int* __restrict__ flag, const float* __restrict__ dinv,
                                const unsigned short* __restrict__ h, float* __restrict__ agg, int E) {
    int gid = blockIdx.x * BLK + threadIdx.x;
    if (gid >= E * WD) return;
    int e = gid / WD;
    int o = gid % WD;
    int s, d;
    if (*flag) { s = idx[2 * e]; d = idx[2 * (E + e)]; }
    else       { s = idx[e];     d = idx[E + e]; }
    float nrm = ew[e] * dinv[d];
    atomicAdd(&agg[d * WD + o], nrm * bf2f(h[s * WD + o]));
}

// fallback reduce+sigmoid
__global__ void reduce_final_kernel(const float* __restrict__ dmat, const float* __restrict__ wfc,
                                    float* __restrict__ acc, int* __restrict__ done,
                                    const float* __restrict__ bfc, float* __restrict__ out,
                                    int M, int nblk) {
    int i = blockIdx.x * BLK + threadIdx.x;
    float v = 0.f;
    if (i < M) v = fmaxf(dmat[i], 0.f) * wfc[i];
#pragma unroll
    for (int off = 32; off > 0; off >>= 1) v += __shfl_down(v, off, 64);
    if ((threadIdx.x & 63) == 0) atomicAdd(acc, v);
    __syncthreads();
    if (threadIdx.x == 0) {
        __threadfence();
        int old = atomicAdd(done, 1);
        if (old == nblk - 1) {
            float x = atomicAdd(acc, 0.f) + *bfc;
            out[0] = 1.f / (1.f + expf(-x));
        }
    }
}

// ---------------------------------------------------------------------------
extern "C" void kernel_launch(void* const* d_in, const int* in_sizes, int n_in,
                              void* d_out, int out_size, void* d_ws, size_t ws_size,
                              hipStream_t stream) {
    const float* feat = (const float*)d_in[0];
    const int*   eidx = (const int*)d_in[1];
    const float* ew   = (const float*)d_in[2];
    const float* W1   = (const float*)d_in[3];
    const float* b1   = (const float*)d_in[4];
    const float* W2   = (const float*)d_in[5];
    const float* b2   = (const float*)d_in[6];
    const float* Wd   = (const float*)d_in[7];
    const float* bd   = (const float*)d_in[8];
    const float* wfc  = (const float*)d_in[9];
    const float* bfc  = (const float*)d_in[10];

    const int N = in_sizes[0] / 128;  // 50000
    const int E = in_sizes[2];        // 1600000

    const int NB   = (N + BNODES - 1) >> BSH;       // buckets (196 @ BSH=8)
    const int NBLK = (E + CHUNK - 1) / CHUNK;       // edge blocks (196 @ CHUNK=8192)

    // workspace layout (units: 4B words)
    float* ws = (float*)d_ws;
    size_t u = 0;
    float* dinv = ws + u; u += N;
    if (u & 1) u++;
    size_t M1 = ((size_t)N * 32 > (size_t)E * 2) ? (size_t)N * 32 : (size_t)E * 2;
    unsigned short* h = (unsigned short*)(ws + u); int2* temp = (int2*)h; u += M1;
    if (u & 1) u++;
    float* agg = ws + u; u += (size_t)N * 64;
    // contiguous zero region: bucketFill[NB] | acc | done  (single memset)
    int* bucketFill = (int*)(ws + u); u += NB;
    float* acc = ws + u; u += 1;
    int* done = (int*)(ws + u); u += 1;
    int* flag = (int*)(ws + u); u += 1;
    int* row  = (int*)(ws + u); u += (size_t)N + 1;
    int* blockBase = (int*)(ws + u); u += (size_t)NBLK * NB;
    unsigned* csrw = (unsigned*)(ws + u); u += (size_t)E;
    size_t need = u * 4;

    float* out = (float*)d_out;

    const int gN = (N + BLK - 1) / BLK;
    const int gE = (E + BLK - 1) / BLK;
    const int gW = (N + 3) / 4;
    const int gM = (N + 63) / 64;
    const int gR = (N * 2 + BLK - 1) / BLK;

    if (ws_size >= need && N <= 65536 && NB <= MAXNB) {
        // ---- deterministic-partition bucket-sort CSR build ----
        hipMemsetAsync(bucketFill, 0, (size_t)(NB + 2) * 4, stream);
        hipLaunchKernelGGL(bucket_hist_kernel, dim3(NBLK), dim3(256), 0, stream,
                           eidx, bucketFill, blockBase, E, NB);
        hipLaunchKernelGGL(bucket_scatter_kernel, dim3(NBLK), dim3(256), 0, stream,
                           eidx, ew, bucketFill, blockBase, temp, E, NB);
        hipLaunchKernelGGL(csr_build_kernel, dim3(NB), dim3(512), 0, stream,
                           temp, bucketFill, csrw, row, dinv, N, NB, E);

        // ---- layers ----
        hipLaunchKernelGGL(mm1_mfma_kernel, dim3(gM), dim3(256), 0, stream,
                           feat, W1, dinv, h, N);
        hipLaunchKernelGGL(gather64_kernel, dim3(gW), dim3(256), 0, stream,
                           row, csrw, h, dinv, b1, agg, N);
        hipLaunchKernelGGL(mm2_mfma_kernel, dim3(gM), dim3(256), 0, stream,
                           agg, W2, dinv, h, N);
        hipLaunchKernelGGL(gather32_disc_kernel, dim3(gW), dim3(256), 0, stream,
                           row, csrw, h, dinv, b2, feat, Wd, (unsigned short*)agg, N);
        hipLaunchKernelGGL(gather2_reduce_kernel, dim3(gW), dim3(256), 0, stream,
                           row, csrw, (const unsigned short*)agg, dinv, bd, wfc,
                           acc, done, bfc, out, N, gW);
    } else {
        // ---- fallback: atomic scatter path ----
        hipLaunchKernelGGL(detect_kernel, dim3(1), dim3(64), 0, stream, eidx, E, flag, acc, done);
        hipLaunchKernelGGL(init_deg_kernel, dim3(gN), dim3(BLK), 0, stream, dinv, N);
        hipLaunchKernelGGL(edge_deg_kernel, dim3(gE), dim3(BLK), 0, stream, eidx, ew, flag, dinv, E);
        hipLaunchKernelGGL(dinv_kernel, dim3(gN), dim3(BLK), 0, stream, dinv, N);

        hipLaunchKernelGGL(mm1_mfma_kernel, dim3(gM), dim3(256), 0, stream, feat, W1, dinv, h, N);
        hipLaunchKernelGGL((init_agg_kernel<64>), dim3((N * 64 + BLK - 1) / BLK), dim3(BLK), 0, stream,
                           h, dinv, b1, agg, N);
        hipLaunchKernelGGL((edge_agg_kernel<64>), dim3((E / BLK) * 64 + 64), dim3(BLK), 0, stream,
                           eidx, ew, flag, dinv, h, agg, E);
        hipLaunchKernelGGL(mm2_mfma_kernel, dim3(gM), dim3(256), 0, stream, agg, W2, dinv, h, N);
        hipLaunchKernelGGL((init_agg_kernel<32>), dim3((N * 32 + BLK - 1) / BLK), dim3(BLK), 0, stream,
                           h, dinv, b2, agg, N);
        hipLaunchKernelGGL((edge_agg_kernel<32>), dim3((E / BLK) * 32 + 32), dim3(BLK), 0, stream,
                           eidx, ew, flag, dinv, h, agg, E);
        hipLaunchKernelGGL(disc_mm_kernel, dim3((N + 255) / 256), dim3(256), 0, stream,
                           agg, feat, Wd, dinv, h, N);
        hipLaunchKernelGGL((init_agg_kernel<2>), dim3((N * 2 + BLK - 1) / BLK), dim3(BLK), 0, stream,
                           h, dinv, bd, agg, N);
        hipLaunchKernelGGL((edge_agg_kernel<2>), dim3((E * 2 + BLK - 1) / BLK), dim3(BLK), 0, stream,
                           eidx, ew, flag, dinv, h, agg, E);
        hipLaunchKernelGGL(reduce_final_kernel, dim3(gR), dim3(BLK), 0, stream,
                           agg, wfc, acc, done, bfc, out, N * 2, gR);
    }
}

// Round 14
// 261.610 us; speedup vs baseline: 2.0866x; 2.0866x over previous
//
#include <hip/hip_runtime.h>
#include <math.h>

#define BLK 256
#define CHUNK 8192
#define BSH 8
#define BNODES 256
#define MAXNB 256

typedef __attribute__((ext_vector_type(8))) short bf8_t;   // 8 bf16
typedef __attribute__((ext_vector_type(4))) float f4_t;    // MFMA acc

// ---------------------------------------------------------------------------
__device__ __forceinline__ unsigned short f2bf(float f) {
    unsigned u = __float_as_uint(f);
    u += 0x7FFFu + ((u >> 16) & 1u);
    return (unsigned short)(u >> 16);
}
__device__ __forceinline__ float bf2f(unsigned short b) {
    return __uint_as_float(((unsigned)b) << 16);
}

// ---------------------------------------------------------------------------
// Fallback-path probe; zeroes acc/done.
__global__ void detect_kernel(const int* __restrict__ idx, int E,
                              int* __restrict__ flag, float* __restrict__ acc,
                              int* __restrict__ done) {
    int t = threadIdx.x;  // 64 threads
    long long j = (long long)t * (E / 64);
    int hi = idx[2 * j + 1];
    unsigned long long b = __ballot(hi != 0);
    if (t == 0) { *flag = (b == 0ULL) ? 1 : 0; *acc = 0.f; *done = 0; }
}

// ---------------------------------------------------------------------------
// K1: per-block bucket histogram; claims per-bucket base via global atomicAdd
// into bucketFill (pre-zeroed by memset). i64 detection inlined.
__global__ __launch_bounds__(256) void bucket_hist_kernel(const int* __restrict__ idx,
                                                          int* __restrict__ bucketFill,
                                                          int* __restrict__ blockBase,
                                                          int E, int NB) {
    __shared__ int hist[MAXNB];
    __shared__ int i64s;
    int t = threadIdx.x;
    for (int i = t; i < NB; i += 256) hist[i] = 0;
    if (t < 64) {
        long long j = (long long)t * (E / 64);
        int hi = idx[2 * j + 1];
        unsigned long long b = __ballot(hi != 0);
        if (t == 0) i64s = (b == 0ULL) ? 1 : 0;
    }
    __syncthreads();
    bool i64 = i64s != 0;
    int e0 = blockIdx.x * CHUNK;
    int e1 = min(e0 + CHUNK, E);
    for (int e = e0 + t; e < e1; e += 256) {
        int d = i64 ? idx[2 * (E + e)] : idx[E + e];
        atomicAdd(&hist[d >> BSH], 1);
    }
    __syncthreads();
    for (int i = t; i < NB; i += 256)
        blockBase[blockIdx.x * NB + i] = atomicAdd(&bucketFill[i], hist[i]);
}

// K3: scatter edges into bucket-partitioned temp as contiguous runs.
// bucketBase derived in-block from bucketFill (NB<=256 scan).
__global__ __launch_bounds__(256) void bucket_scatter_kernel(const int* __restrict__ idx,
                                                             const float* __restrict__ ew,
                                                             const int* __restrict__ bucketFill,
                                                             const int* __restrict__ blockBase,
                                                             int2* __restrict__ temp,
                                                             int E, int NB) {
    __shared__ int base[MAXNB];
    __shared__ int fill[MAXNB];
    __shared__ int s[256];
    __shared__ int i64s;
    int t = threadIdx.x;
    int v = (t < NB) ? bucketFill[t] : 0;
    s[t] = v;
    if (t < 64) {
        long long j = (long long)t * (E / 64);
        int hi = idx[2 * j + 1];
        unsigned long long b = __ballot(hi != 0);
        if (t == 0) i64s = (b == 0ULL) ? 1 : 0;
    }
    __syncthreads();
    for (int off = 1; off < 256; off <<= 1) {
        int x = (t >= off) ? s[t - off] : 0;
        __syncthreads();
        s[t] += x;
        __syncthreads();
    }
    if (t < NB) {
        base[t] = (s[t] - v) + blockBase[blockIdx.x * NB + t];
        fill[t] = 0;
    }
    __syncthreads();
    bool i64 = i64s != 0;
    int e0 = blockIdx.x * CHUNK;
    int e1 = min(e0 + CHUNK, E);
    for (int e = e0 + t; e < e1; e += 256) {
        int s_, d;
        if (i64) { s_ = idx[2 * e]; d = idx[2 * (E + e)]; }
        else     { s_ = idx[e];     d = idx[E + e]; }
        float w = ew[e];
        int b = d >> BSH;
        int pos = base[b] + atomicAdd(&fill[b], 1);
        temp[pos] = make_int2(s_ | ((d & (BNODES - 1)) << 16), __float_as_int(w));
    }
}

// K4: per-bucket counting sort into packed CSR + dinv + row (one block/bucket)
// csrw[p] = src(16b) | raw bf16(w)<<16  (dinv folded into dense layers).
__global__ __launch_bounds__(512) void csr_build_kernel(const int2* __restrict__ temp,
                                                        const int* __restrict__ bucketFill,
                                                        unsigned* __restrict__ csrw,
                                                        int* __restrict__ row,
                                                        float* __restrict__ dinv,
                                                        int N, int NB, int E) {
    __shared__ int cnt[BNODES];
    __shared__ float dw[BNODES];
    __shared__ int offs[BNODES];
    __shared__ int sb[256];
    int bkt = blockIdx.x;
    int t = threadIdx.x;
    int node0 = bkt << BSH;
    int nn = min(BNODES, N - node0);
    if (t < BNODES) { cnt[t] = 0; dw[t] = 0.f; }
    if (t < 256) sb[t] = (t < NB) ? bucketFill[t] : 0;
    __syncthreads();
    for (int off = 1; off < 256; off <<= 1) {
        int x = 0;
        if (t < 256 && t >= off) x = sb[t - off];
        __syncthreads();
        if (t < 256) sb[t] += x;
        __syncthreads();
    }
    int p0 = (bkt > 0) ? sb[bkt - 1] : 0;
    int p1 = sb[bkt];
    for (int p = p0 + t; p < p1; p += 512) {
        int2 v = temp[p];
        int dl = (v.x >> 16) & (BNODES - 1);
        atomicAdd(&cnt[dl], 1);
        atomicAdd(&dw[dl], __int_as_float(v.y));
    }
    __syncthreads();
    int v = 0;
    if (t < BNODES) { v = cnt[t]; offs[t] = v; }
    __syncthreads();
    for (int off = 1; off < BNODES; off <<= 1) {
        int x = 0;
        if (t < BNODES && t >= off) x = offs[t - off];
        __syncthreads();
        if (t < BNODES) offs[t] += x;
        __syncthreads();
    }
    if (t < BNODES) {
        int excl = offs[t] - v;
        if (t < nn) {
            row[node0 + t] = p0 + excl;
            dinv[node0 + t] = rsqrtf(1.f + dw[t]);
        }
        offs[t] = excl;
    }
    if (bkt == NB - 1 && t == 0) row[N] = E;
    __syncthreads();
    if (t < BNODES) cnt[t] = 0;  // reuse as fill
    __syncthreads();
    for (int p = p0 + t; p < p1; p += 512) {
        int2 v2 = temp[p];
        int dl = (v2.x >> 16) & (BNODES - 1);
        int pos = p0 + offs[dl] + atomicAdd(&cnt[dl], 1);
        unsigned wb = (unsigned)v2.y;
        wb += 0x7FFFu + ((wb >> 16) & 1u);
        csrw[pos] = ((unsigned)v2.x & 0xFFFFu) | (wb & 0xFFFF0000u);
    }
}

// ---------------------------------------------------------------------------
// gather64: out[n,o] = bias[o] + dinv[n]*( h'[n,o] + sum w_raw*h'[src,o] )
__global__ __launch_bounds__(256) void gather64_kernel(const int* __restrict__ row,
                                                       const unsigned* __restrict__ csrw,
                                                       const unsigned short* __restrict__ h,
                                                       const float* __restrict__ dinv,
                                                       const float* __restrict__ bias,
                                                       float* __restrict__ out, int N) {
    int wid = (blockIdx.x * 256 + threadIdx.x) >> 6;
    int o = threadIdx.x & 63;
    if (wid >= N) return;
    float di = dinv[wid];
    int p0 = row[wid], p1 = row[wid + 1];
    const unsigned short* hb = h + o;
    float es[4] = {0.f, 0.f, 0.f, 0.f};
    for (int p = p0; p < p1; p += 64) {
        int q = p + o;
        unsigned pe = (q < p1) ? csrw[q] : 0u;
        int m = min(64, p1 - p);
        int mp = (m + 15) & ~15;
        for (int j = 0; j < mp; j += 16) {
            unsigned ee[16];
            float hh[16];
#pragma unroll
            for (int u = 0; u < 16; ++u) ee[u] = (unsigned)__shfl((int)pe, j + u, 64);
#pragma unroll
            for (int u = 0; u < 16; ++u) hh[u] = bf2f(hb[(ee[u] & 0xFFFFu) * 64]);
#pragma unroll
            for (int u = 0; u < 16; ++u)
                es[u & 3] = fmaf(__uint_as_float(ee[u] & 0xFFFF0000u), hh[u], es[u & 3]);
        }
    }
    float e01 = es[0] + es[1], e23 = es[2] + es[3];
    out[wid * 64 + o] = bias[o] + di * (bf2f(h[(size_t)wid * 64 + o]) + e01 + e23);
}

// gather32 + discriminator fused: compute z row (32 wide), tanh, tile to 128,
// add F, dot with Wd -> dpre' = dinv*(x@Wd) written as 2 bf16 per node.
__global__ __launch_bounds__(256) void gather32_disc_kernel(const int* __restrict__ row,
                                                            const unsigned* __restrict__ csrw,
                                                            const unsigned short* __restrict__ h,
                                                            const float* __restrict__ dinv,
                                                            const float* __restrict__ bias,
                                                            const float* __restrict__ F,
                                                            const float* __restrict__ Wd,
                                                            unsigned short* __restrict__ hout,
                                                            int N) {
    __shared__ float Ws[256];
    if (threadIdx.x < 256) Ws[threadIdx.x] = Wd[threadIdx.x];
    __syncthreads();
    int wid = (blockIdx.x * 256 + threadIdx.x) >> 6;
    int lane = threadIdx.x & 63;
    int o = lane & 31;
    int g = lane >> 5;
    if (wid >= N) return;
    float di = dinv[wid];
    int p0 = row[wid], p1 = row[wid + 1];
    const unsigned short* hb = h + o;
    float es[4] = {0.f, 0.f, 0.f, 0.f};
    for (int p = p0; p < p1; p += 64) {
        int q = p + lane;
        unsigned pe = (q < p1) ? csrw[q] : 0u;
        int m = min(64, p1 - p);
        int mp = (m + 15) & ~15;
        for (int j = g; j < mp; j += 16) {
            unsigned ee[8];
            float hh[8];
#pragma unroll
            for (int u = 0; u < 8; ++u) ee[u] = (unsigned)__shfl((int)pe, j + 2 * u, 64);
#pragma unroll
            for (int u = 0; u < 8; ++u) hh[u] = bf2f(hb[(ee[u] & 0xFFFFu) * 32]);
#pragma unroll
            for (int u = 0; u < 8; ++u)
                es[u & 3] = fmaf(__uint_as_float(ee[u] & 0xFFFF0000u), hh[u], es[u & 3]);
        }
    }
    float es_t = (es[0] + es[1]) + (es[2] + es[3]);
    es_t += __shfl_down(es_t, 32, 64);
    // lanes 0..31 hold full z row for this node
    float a0 = 0.f, a1 = 0.f;
    if (g == 0) {
        float zt = tanhf(bias[o] + di * (bf2f(h[wid * 32 + o]) + es_t));
        const float* fr = F + (size_t)wid * 128;
#pragma unroll
        for (int j = 0; j < 4; ++j) {
            int c = o + 32 * j;
            float xv = zt + fr[c];
            a0 = fmaf(xv, Ws[c * 2 + 0], a0);
            a1 = fmaf(xv, Ws[c * 2 + 1], a1);
        }
    }
#pragma unroll
    for (int off = 16; off > 0; off >>= 1) {
        a0 += __shfl_down(a0, off, 64);
        a1 += __shfl_down(a1, off, 64);
    }
    if (lane == 0) {
        ushort2 ov;
        ov.x = f2bf(di * a0);
        ov.y = f2bf(di * a1);
        ((ushort2*)hout)[wid] = ov;
    }
}

// gather2 + per-node logit contribution (NO device atomics here — R13 showed
// 12.5k same-line atomics+fences cost ~300us). contrib[n] written plainly.
__global__ __launch_bounds__(256) void gather2_contrib_kernel(const int* __restrict__ row,
                                                              const unsigned* __restrict__ csrw,
                                                              const unsigned short* __restrict__ h,
                                                              const float* __restrict__ dinv,
                                                              const float* __restrict__ bias,
                                                              const float* __restrict__ wfc,
                                                              float* __restrict__ contrib,
                                                              int N) {
    const unsigned* hp = (const unsigned*)h;
    int wid = (blockIdx.x * 256 + threadIdx.x) >> 6;
    int lane = threadIdx.x & 63;
    if (wid >= N) return;
    float di = dinv[wid];
    int p0 = row[wid], p1 = row[wid + 1];
    float a0 = 0.f, a1 = 0.f, b0 = 0.f, b1 = 0.f;
    int p = p0 + lane;
    for (; p + 64 < p1; p += 128) {
        unsigned pe0 = csrw[p];
        unsigned pe1 = csrw[p + 64];
        unsigned hw0 = hp[pe0 & 0xFFFFu];
        unsigned hw1 = hp[pe1 & 0xFFFFu];
        float w0 = __uint_as_float(pe0 & 0xFFFF0000u);
        float w1 = __uint_as_float(pe1 & 0xFFFF0000u);
        a0 = fmaf(w0, __uint_as_float(hw0 << 16), a0);
        a1 = fmaf(w0, __uint_as_float(hw0 & 0xFFFF0000u), a1);
        b0 = fmaf(w1, __uint_as_float(hw1 << 16), b0);
        b1 = fmaf(w1, __uint_as_float(hw1 & 0xFFFF0000u), b1);
    }
    if (p < p1) {
        unsigned pe0 = csrw[p];
        unsigned hw0 = hp[pe0 & 0xFFFFu];
        float w0 = __uint_as_float(pe0 & 0xFFFF0000u);
        a0 = fmaf(w0, __uint_as_float(hw0 << 16), a0);
        a1 = fmaf(w0, __uint_as_float(hw0 & 0xFFFF0000u), a1);
    }
    a0 += b0; a1 += b1;
#pragma unroll
    for (int off = 32; off > 0; off >>= 1) {
        a0 += __shfl_down(a0, off, 64);
        a1 += __shfl_down(a1, off, 64);
    }
    if (lane == 0) {
        unsigned hw = hp[wid];
        float v0 = bias[0] + di * (__uint_as_float(hw << 16) + a0);
        float v1 = bias[1] + di * (__uint_as_float(hw & 0xFFFF0000u) + a1);
        contrib[wid] = fmaxf(v0, 0.f) * wfc[wid * 2 + 0] + fmaxf(v1, 0.f) * wfc[wid * 2 + 1];
    }
}

// sum contribs (196 blocks) + last-block sigmoid
__global__ void sum_final_kernel(const float* __restrict__ contrib,
                                 float* __restrict__ acc, int* __restrict__ done,
                                 const float* __restrict__ bfc, float* __restrict__ out,
                                 int N, int nblk) {
    int i = blockIdx.x * BLK + threadIdx.x;
    float v = (i < N) ? contrib[i] : 0.f;
#pragma unroll
    for (int off = 32; off > 0; off >>= 1) v += __shfl_down(v, off, 64);
    if ((threadIdx.x & 63) == 0) atomicAdd(acc, v);
    __syncthreads();
    if (threadIdx.x == 0) {
        __threadfence();
        int old = atomicAdd(done, 1);
        if (old == nblk - 1) {
            float x = atomicAdd(acc, 0.f) + *bfc;
            out[0] = 1.f / (1.f + expf(-x));
        }
    }
}

// ---------------------------------------------------------------------------
// mm1 (MFMA): Y[N,64] = dinv[n] * (X[N,128] @ W[128,64]), bf16 out.
__global__ __launch_bounds__(256) void mm1_mfma_kernel(const float* __restrict__ X,
                                                       const float* __restrict__ W,
                                                       const float* __restrict__ dinv,
                                                       unsigned short* __restrict__ Y, int N) {
    __shared__ unsigned short Wf[4 * 4 * 64 * 8];  // [kt][ct][lane][j], 16 KB
    int t = threadIdx.x;
    for (int i = t; i < 8192; i += 256) {
        int j = i & 7;
        int lane = (i >> 3) & 63;
        int ct = (i >> 9) & 3;
        int kt = i >> 11;
        int k = kt * 32 + (lane >> 4) * 8 + j;
        int c = ct * 16 + (lane & 15);
        Wf[i] = f2bf(W[k * 64 + c]);
    }
    __syncthreads();
    int wave = t >> 6, lane = t & 63;
    int row0 = blockIdx.x * 64 + wave * 16;
    if (row0 >= N) return;
    int r = row0 + (lane & 15);
    int kq = (lane >> 4) * 8;
    bool rv = r < N;
    f4_t acc0 = {0.f, 0.f, 0.f, 0.f}, acc1 = acc0, acc2 = acc0, acc3 = acc0;
    const bf8_t* wf = (const bf8_t*)Wf;
#pragma unroll
    for (int kt = 0; kt < 4; ++kt) {
        bf8_t a = {0, 0, 0, 0, 0, 0, 0, 0};
        if (rv) {
            const float4* ap = (const float4*)(X + (size_t)r * 128 + kt * 32 + kq);
            float4 lo = ap[0], hi = ap[1];
            a[0] = (short)f2bf(lo.x); a[1] = (short)f2bf(lo.y);
            a[2] = (short)f2bf(lo.z); a[3] = (short)f2bf(lo.w);
            a[4] = (short)f2bf(hi.x); a[5] = (short)f2bf(hi.y);
            a[6] = (short)f2bf(hi.z); a[7] = (short)f2bf(hi.w);
        }
        bf8_t b0 = wf[(kt * 4 + 0) * 64 + lane];
        bf8_t b1 = wf[(kt * 4 + 1) * 64 + lane];
        bf8_t b2 = wf[(kt * 4 + 2) * 64 + lane];
        bf8_t b3 = wf[(kt * 4 + 3) * 64 + lane];
        acc0 = __builtin_amdgcn_mfma_f32_16x16x32_bf16(a, b0, acc0, 0, 0, 0);
        acc1 = __builtin_amdgcn_mfma_f32_16x16x32_bf16(a, b1, acc1, 0, 0, 0);
        acc2 = __builtin_amdgcn_mfma_f32_16x16x32_bf16(a, b2, acc2, 0, 0, 0);
        acc3 = __builtin_amdgcn_mfma_f32_16x16x32_bf16(a, b3, acc3, 0, 0, 0);
    }
    int colb = lane & 15;
    int rbase = row0 + (lane >> 4) * 4;
#pragma unroll
    for (int reg = 0; reg < 4; ++reg) {
        int rr = rbase + reg;
        if (rr < N) {
            float dv = dinv[rr];
            Y[(size_t)rr * 64 + colb]      = f2bf(dv * acc0[reg]);
            Y[(size_t)rr * 64 + 16 + colb] = f2bf(dv * acc1[reg]);
            Y[(size_t)rr * 64 + 32 + colb] = f2bf(dv * acc2[reg]);
            Y[(size_t)rr * 64 + 48 + colb] = f2bf(dv * acc3[reg]);
        }
    }
}

// mm2 (MFMA): Y[N,32] = dinv[n] * (relu(A[N,64]) @ W[64,32]), bf16 out.
__global__ __launch_bounds__(256) void mm2_mfma_kernel(const float* __restrict__ A,
                                                       const float* __restrict__ W,
                                                       const float* __restrict__ dinv,
                                                       unsigned short* __restrict__ Y, int N) {
    __shared__ unsigned short Wf[2 * 2 * 64 * 8];  // 4 KB
    int t = threadIdx.x;
    for (int i = t; i < 2048; i += 256) {
        int j = i & 7;
        int lane = (i >> 3) & 63;
        int ct = (i >> 9) & 1;
        int kt = i >> 10;
        int k = kt * 32 + (lane >> 4) * 8 + j;
        int c = ct * 16 + (lane & 15);
        Wf[i] = f2bf(W[k * 32 + c]);
    }
    __syncthreads();
    int wave = t >> 6, lane = t & 63;
    int row0 = blockIdx.x * 64 + wave * 16;
    if (row0 >= N) return;
    int r = row0 + (lane & 15);
    int kq = (lane >> 4) * 8;
    bool rv = r < N;
    f4_t acc0 = {0.f, 0.f, 0.f, 0.f}, acc1 = acc0;
    const bf8_t* wf = (const bf8_t*)Wf;
#pragma unroll
    for (int kt = 0; kt < 2; ++kt) {
        bf8_t a = {0, 0, 0, 0, 0, 0, 0, 0};
        if (rv) {
            const float4* ap = (const float4*)(A + (size_t)r * 64 + kt * 32 + kq);
            float4 lo = ap[0], hi = ap[1];
            a[0] = (short)f2bf(fmaxf(lo.x, 0.f)); a[1] = (short)f2bf(fmaxf(lo.y, 0.f));
            a[2] = (short)f2bf(fmaxf(lo.z, 0.f)); a[3] = (short)f2bf(fmaxf(lo.w, 0.f));
            a[4] = (short)f2bf(fmaxf(hi.x, 0.f)); a[5] = (short)f2bf(fmaxf(hi.y, 0.f));
            a[6] = (short)f2bf(fmaxf(hi.z, 0.f)); a[7] = (short)f2bf(fmaxf(hi.w, 0.f));
        }
        bf8_t b0 = wf[(kt * 2 + 0) * 64 + lane];
        bf8_t b1 = wf[(kt * 2 + 1) * 64 + lane];
        acc0 = __builtin_amdgcn_mfma_f32_16x16x32_bf16(a, b0, acc0, 0, 0, 0);
        acc1 = __builtin_amdgcn_mfma_f32_16x16x32_bf16(a, b1, acc1, 0, 0, 0);
    }
    int colb = lane & 15;
    int rbase = row0 + (lane >> 4) * 4;
#pragma unroll
    for (int reg = 0; reg < 4; ++reg) {
        int rr = rbase + reg;
        if (rr < N) {
            float dv = dinv[rr];
            Y[(size_t)rr * 32 + colb]      = f2bf(dv * acc0[reg]);
            Y[(size_t)rr * 32 + 16 + colb] = f2bf(dv * acc1[reg]);
        }
    }
}

// standalone disc (fallback path only)
__global__ __launch_bounds__(256) void disc_mm_kernel(const float* __restrict__ Z,
                                                      const float* __restrict__ F,
                                                      const float* __restrict__ Wd,
                                                      const float* __restrict__ dinv,
                                                      unsigned short* __restrict__ Y, int N) {
    __shared__ float Ws[256];
    if (threadIdx.x < 256) Ws[threadIdx.x] = Wd[threadIdx.x];
    __syncthreads();
    int n = blockIdx.x * 256 + threadIdx.x;
    if (n >= N) return;
    float zt[32];
#pragma unroll
    for (int j = 0; j < 32; ++j) zt[j] = tanhf(Z[n * 32 + j]);
    float a0 = 0.f, a1 = 0.f;
    const float* fr = F + (size_t)n * 128;
#pragma unroll 4
    for (int c = 0; c < 128; ++c) {
        float xv = zt[c & 31] + fr[c];
        a0 = fmaf(xv, Ws[c * 2 + 0], a0);
        a1 = fmaf(xv, Ws[c * 2 + 1], a1);
    }
    float dv = dinv[n];
    ushort2 o;
    o.x = f2bf(dv * a0); o.y = f2bf(dv * a1);
    ((ushort2*)Y)[n] = o;
}

// ---------------------------------------------------------------------------
// Fallback (atomic scatter) kernels — h' = dinv*h convention
__global__ void init_deg_kernel(float* __restrict__ deg, int N) {
    int n = blockIdx.x * BLK + threadIdx.x;
    if (n < N) deg[n] = 1.0f;
}

__global__ void edge_deg_kernel(const int* __restrict__ idx, const float* __restrict__ ew,
                                const int* __restrict__ flag, float* __restrict__ deg, int E) {
    int e = blockIdx.x * BLK + threadIdx.x;
    if (e >= E) return;
    int d = (*flag) ? idx[2 * (E + e)] : idx[E + e];
    atomicAdd(&deg[d], ew[e]);
}

__global__ void dinv_kernel(float* __restrict__ deg, int N) {
    int n = blockIdx.x * BLK + threadIdx.x;
    if (n < N) deg[n] = rsqrtf(deg[n]);
}

template <int WD>
__global__ void init_agg_kernel(const unsigned short* __restrict__ h, const float* __restrict__ dinv,
                                const float* __restrict__ bias, float* __restrict__ agg, int N) {
    int i = blockIdx.x * BLK + threadIdx.x;
    if (i >= N * WD) return;
    int n = i / WD, o = i % WD;
    float di = dinv[n];
    agg[i] = bias[o] + di * bf2f(h[i]);
}

template <int WD>
__global__ void edge_agg_kernel(const int* __restrict__ idx, const float* __restrict__ ew,
                                const int* __restrict__ flag, const float* __restrict__ dinv,
                                const unsigned short* __restrict__ h, float* __restrict__ agg, int E) {
    int gid = blockIdx.x * BLK + threadIdx.x;
    if (gid >= E * WD) return;
    int e = gid / WD;
    int o = gid % WD;
    int s, d;
    if (*flag) { s = idx[2 * e]; d = idx[2 * (E + e)]; }
    else       { s = idx[e];     d = idx[E + e]; }
    float nrm = ew[e] * dinv[d];
    atomicAdd(&agg[d * WD + o], nrm * bf2f(h[s * WD + o]));
}

// fallback reduce+sigmoid (relu(d)*wfc over N*2 elements)
__global__ void reduce_final_kernel(const float* __restrict__ dmat, const float* __restrict__ wfc,
                                    float* __restrict__ acc, int* __restrict__ done,
                                    const float* __restrict__ bfc, float* __restrict__ out,
                                    int M, int nblk) {
    int i = blockIdx.x * BLK + threadIdx.x;
    float v = 0.f;
    if (i < M) v = fmaxf(dmat[i], 0.f) * wfc[i];
#pragma unroll
    for (int off = 32; off > 0; off >>= 1) v += __shfl_down(v, off, 64);
    if ((threadIdx.x & 63) == 0) atomicAdd(acc, v);
    __syncthreads();
    if (threadIdx.x == 0) {
        __threadfence();
        int old = atomicAdd(done, 1);
        if (old == nblk - 1) {
            float x = atomicAdd(acc, 0.f) + *bfc;
            out[0] = 1.f / (1.f + expf(-x));
        }
    }
}

// ---------------------------------------------------------------------------
extern "C" void kernel_launch(void* const* d_in, const int* in_sizes, int n_in,
                              void* d_out, int out_size, void* d_ws, size_t ws_size,
                              hipStream_t stream) {
    const float* feat = (const float*)d_in[0];
    const int*   eidx = (const int*)d_in[1];
    const float* ew   = (const float*)d_in[2];
    const float* W1   = (const float*)d_in[3];
    const float* b1   = (const float*)d_in[4];
    const float* W2   = (const float*)d_in[5];
    const float* b2   = (const float*)d_in[6];
    const float* Wd   = (const float*)d_in[7];
    const float* bd   = (const float*)d_in[8];
    const float* wfc  = (const float*)d_in[9];
    const float* bfc  = (const float*)d_in[10];

    const int N = in_sizes[0] / 128;  // 50000
    const int E = in_sizes[2];        // 1600000

    const int NB   = (N + BNODES - 1) >> BSH;       // buckets (196 @ BSH=8)
    const int NBLK = (E + CHUNK - 1) / CHUNK;       // edge blocks (196 @ CHUNK=8192)

    // workspace layout (units: 4B words)
    float* ws = (float*)d_ws;
    size_t u = 0;
    float* dinv = ws + u; u += N;
    if (u & 1) u++;
    size_t M1 = ((size_t)N * 32 > (size_t)E * 2) ? (size_t)N * 32 : (size_t)E * 2;
    unsigned short* h = (unsigned short*)(ws + u); int2* temp = (int2*)h; u += M1;
    if (u & 1) u++;
    float* agg = ws + u; u += (size_t)N * 64;   // dpre' lives in agg[0..N) words; contrib in agg[N..2N)
    // contiguous zero region: bucketFill[NB] | acc | done  (single memset)
    int* bucketFill = (int*)(ws + u); u += NB;
    float* acc = ws + u; u += 1;
    int* done = (int*)(ws + u); u += 1;
    int* flag = (int*)(ws + u); u += 1;
    int* row  = (int*)(ws + u); u += (size_t)N + 1;
    int* blockBase = (int*)(ws + u); u += (size_t)NBLK * NB;
    unsigned* csrw = (unsigned*)(ws + u); u += (size_t)E;
    size_t need = u * 4;

    float* out = (float*)d_out;
    float* contrib = agg + N;   // disjoint from dpre' (agg[0..N) words as ushort2)

    const int gN = (N + BLK - 1) / BLK;
    const int gE = (E + BLK - 1) / BLK;
    const int gW = (N + 3) / 4;
    const int gM = (N + 63) / 64;
    const int gS = (N + BLK - 1) / BLK;
    const int gR = (N * 2 + BLK - 1) / BLK;

    if (ws_size >= need && N <= 65536 && NB <= MAXNB) {
        // ---- deterministic-partition bucket-sort CSR build ----
        hipMemsetAsync(bucketFill, 0, (size_t)(NB + 2) * 4, stream);
        hipLaunchKernelGGL(bucket_hist_kernel, dim3(NBLK), dim3(256), 0, stream,
                           eidx, bucketFill, blockBase, E, NB);
        hipLaunchKernelGGL(bucket_scatter_kernel, dim3(NBLK), dim3(256), 0, stream,
                           eidx, ew, bucketFill, blockBase, temp, E, NB);
        hipLaunchKernelGGL(csr_build_kernel, dim3(NB), dim3(512), 0, stream,
                           temp, bucketFill, csrw, row, dinv, N, NB, E);

        // ---- layers ----
        hipLaunchKernelGGL(mm1_mfma_kernel, dim3(gM), dim3(256), 0, stream,
                           feat, W1, dinv, h, N);
        hipLaunchKernelGGL(gather64_kernel, dim3(gW), dim3(256), 0, stream,
                           row, csrw, h, dinv, b1, agg, N);
        hipLaunchKernelGGL(mm2_mfma_kernel, dim3(gM), dim3(256), 0, stream,
                           agg, W2, dinv, h, N);
        hipLaunchKernelGGL(gather32_disc_kernel, dim3(gW), dim3(256), 0, stream,
                           row, csrw, h, dinv, b2, feat, Wd, (unsigned short*)agg, N);
        hipLaunchKernelGGL(gather2_contrib_kernel, dim3(gW), dim3(256), 0, stream,
                           row, csrw, (const unsigned short*)agg, dinv, bd, wfc, contrib, N);
        hipLaunchKernelGGL(sum_final_kernel, dim3(gS), dim3(BLK), 0, stream,
                           contrib, acc, done, bfc, out, N, gS);
    } else {
        // ---- fallback: atomic scatter path ----
        hipLaunchKernelGGL(detect_kernel, dim3(1), dim3(64), 0, stream, eidx, E, flag, acc, done);
        hipLaunchKernelGGL(init_deg_kernel, dim3(gN), dim3(BLK), 0, stream, dinv, N);
        hipLaunchKernelGGL(edge_deg_kernel, dim3(gE), dim3(BLK), 0, stream, eidx, ew, flag, dinv, E);
        hipLaunchKernelGGL(dinv_kernel, dim3(gN), dim3(BLK), 0, stream, dinv, N);

        hipLaunchKernelGGL(mm1_mfma_kernel, dim3(gM), dim3(256), 0, stream, feat, W1, dinv, h, N);
        hipLaunchKernelGGL((init_agg_kernel<64>), dim3((N * 64 + BLK - 1) / BLK), dim3(BLK), 0, stream,
                           h, dinv, b1, agg, N);
        hipLaunchKernelGGL((edge_agg_kernel<64>), dim3((E / BLK) * 64 + 64), dim3(BLK), 0, stream,
                           eidx, ew, flag, dinv, h, agg, E);
        hipLaunchKernelGGL(mm2_mfma_kernel, dim3(gM), dim3(256), 0, stream, agg, W2, dinv, h, N);
        hipLaunchKernelGGL((init_agg_kernel<32>), dim3((N * 32 + BLK - 1) / BLK), dim3(BLK), 0, stream,
                           h, dinv, b2, agg, N);
        hipLaunchKernelGGL((edge_agg_kernel<32>), dim3((E / BLK) * 32 + 32), dim3(BLK), 0, stream,
                           eidx, ew, flag, dinv, h, agg, E);
        hipLaunchKernelGGL(disc_mm_kernel, dim3((N + 255) / 256), dim3(256), 0, stream,
                           agg, feat, Wd, dinv, h, N);
        hipLaunchKernelGGL((init_agg_kernel<2>), dim3((N * 2 + BLK - 1) / BLK), dim3(BLK), 0, stream,
                           h, dinv, bd, agg, N);
        hipLaunchKernelGGL((edge_agg_kernel<2>), dim3((E * 2 + BLK - 1) / BLK), dim3(BLK), 0, stream,
                           eidx, ew, flag, dinv, h, agg, E);
        hipLaunchKernelGGL(reduce_final_kernel, dim3(gR), dim3(BLK), 0, stream,
                           agg, wfc, acc, done, bfc, out, N * 2, gR);
    }
}